// Round 2
// baseline (21084.882 us; speedup 1.0000x reference)
//
#include <hip/hip_runtime.h>
#include <hip/hip_cooperative_groups.h>
#include <stdint.h>
#include <stddef.h>

// Variational-dropout LSTM, SEQ=256, B=64, IN=H=1024, fp32 I/O.
//
// R2: single persistent cooperative kernel (256 blocks x 512 threads), weights
// held in registers (32 VGPRs/lane), one grid.sync per step. Block bk owns
// hidden cols [bk*4, bk*4+4) for ALL 4 gates (gate-interleaved N mapping:
// n_local = jh*4 + g) so the LSTM cell is block-local and c stays in
// registers for the whole sequence. Waves 0-3: recurrent GEMM (K=1024 split
// 4x256) + reduce + cell. Waves 4-7: x-projection GEMM for step s+1
// (software-pipelined, off the critical path). Cross-wave reduce via
// conflict-free float4 LDS; gate gather via shfl_xor(1,2,3) + 2-bit selects.

namespace cg = cooperative_groups;

typedef __attribute__((ext_vector_type(8))) __bf16 bf16x8;
typedef __attribute__((ext_vector_type(4))) float  f32x4;
typedef unsigned short u16;

__device__ __forceinline__ u16 f2bf(float f) {
  union { float f; unsigned u; } v; v.f = f;
  unsigned r = v.u + 0x7FFFu + ((v.u >> 16) & 1u);   // RNE
  return (u16)(r >> 16);
}

__device__ __forceinline__ float sigm(float x) {
  return __builtin_amdgcn_rcpf(1.f + __expf(-x));
}
__device__ __forceinline__ float tanh_fast(float x) {
  float xc = fminf(15.f, fmaxf(-15.f, x));
  float t = __expf(-2.f * xc);
  return (1.f - t) * __builtin_amdgcn_rcpf(1.f + t);
}
__device__ __forceinline__ float pick4(int idx, float v0, float v1, float v2, float v3) {
  float lo = (idx & 1) ? v1 : v0;
  float hi = (idx & 1) ? v3 : v2;
  return (idx & 2) ? hi : lo;
}

// ws layout (bytes):
//  Wp   @ 0         : 256 blk x 64 kcw x 64 l x 8 e bf16 = 16777216
//                     (kcw<32: W_ih K-half; kcw>=32: W_hh K-half; gate-interleaved N)
//  Ap   @ 16777216  : 256 s x 4 m x 32 kwg x 64 l x 8 e bf16 = 33554432
//  mh0  @ 50331648  : 4 m x 32 kwg x 64 l x 8 e bf16 = 131072
//  mh1  @ 50462720  : 131072
//  bias @ 50593792  : 4096 f32 = 16384

__global__ __launch_bounds__(256) void prep_kernel(
    const float* __restrict__ x, const float* __restrict__ h0,
    const float* __restrict__ mask_x, const float* __restrict__ mask_h,
    const float* __restrict__ Wih, const float* __restrict__ Whh,
    const float* __restrict__ bih, const float* __restrict__ bhh,
    u16* __restrict__ Wp, u16* __restrict__ Ap, u16* __restrict__ mhp0,
    float* __restrict__ bias)
{
  const unsigned idx = blockIdx.x * 256u + threadIdx.x;  // 0 .. 16777215

  // Ap[s][m][kwg][l][e] = bf16( x[s][b][k] * mask_x[b][k] )
  //   b = m*16 + (l&15), k = kwg*32 + (l>>4)*8 + e
  {
    const unsigned e   = idx & 7u;
    const unsigned l   = (idx >> 3) & 63u;
    const unsigned kwg = (idx >> 9) & 31u;
    const unsigned m   = (idx >> 14) & 3u;
    const unsigned s   = idx >> 16;
    const unsigned b   = m * 16u + (l & 15u);
    const unsigned k   = kwg * 32u + (l >> 4) * 8u + e;
    Ap[idx] = f2bf(x[((size_t)s * 64u + b) * 1024u + k] * mask_x[b * 1024u + k]);
  }
  // Wp[bk][kcw][l][e]: n = g*1024 + bk*4 + jh, with nl = l&15 = jh*4 + g
  if (idx < 8388608u) {
    const unsigned e   = idx & 7u;
    const unsigned l   = (idx >> 3) & 63u;
    const unsigned kcw = (idx >> 9) & 63u;
    const unsigned bk  = idx >> 15;
    const unsigned nl  = l & 15u;
    const unsigned n   = (nl & 3u) * 1024u + bk * 4u + (nl >> 2);
    const unsigned kc  = kcw * 32u + (l >> 4) * 8u + e;
    const float v = (kc < 1024u) ? Wih[n * 1024u + kc]
                                 : Whh[n * 1024u + (kc - 1024u)];
    Wp[idx] = f2bf(v);
  }
  // mh0[m][kwg][l][e] = bf16(h0 * mask_h)
  if (idx < 65536u) {
    const unsigned e   = idx & 7u;
    const unsigned l   = (idx >> 3) & 63u;
    const unsigned kwg = (idx >> 9) & 31u;
    const unsigned m   = idx >> 14;
    const unsigned b   = m * 16u + (l & 15u);
    const unsigned k   = kwg * 32u + (l >> 4) * 8u + e;
    mhp0[idx] = f2bf(h0[b * 1024u + k] * mask_h[b * 1024u + k]);
  }
  if (idx < 4096u) bias[idx] = bih[idx] + bhh[idx];
}

__global__ __launch_bounds__(512, 2) void lstm_persist(
    const u16* __restrict__ Ap, const u16* __restrict__ Wp,
    const float* __restrict__ bias,
    u16* __restrict__ mh0, u16* __restrict__ mh1,
    const float* __restrict__ c0, const float* __restrict__ mask_h,
    float* __restrict__ out)
{
  cg::grid_group grid = cg::this_grid();

  __shared__ f32x4 ldsH[4][4][64];     // [h-wave][tile][lane]  16 KB
  __shared__ f32x4 ldsX[2][4][4][64];  // [pingpong][x-wave][tile][lane] 32 KB

  const int tid = threadIdx.x;
  const int w   = tid >> 6;          // 0..7
  const int l   = tid & 63;
  const int bk  = blockIdx.x;        // 0..255: hidden cols bk*4 .. bk*4+3
  const bool xw = (w >= 4);
  const int ws4 = w & 3;

  // ---- load weight fragments into registers (once) ----
  const bf16x8* WpV = (const bf16x8*)Wp;
  bf16x8 wf[8];
  {
    const int kcw0 = xw ? (ws4 * 8) : (32 + ws4 * 8);  // x half / h half of K
    #pragma unroll
    for (int kw = 0; kw < 8; ++kw)
      wf[kw] = WpV[(bk * 64 + kcw0 + kw) * 64 + l];
  }
  const bf16x8* ApV = (const bf16x8*)Ap;
  const bf16x8* mhV0 = (const bf16x8*)mh0;
  const bf16x8* mhV1 = (const bf16x8*)mh1;

  // ---- cell-lane state (waves 0-3); wave ws4 owns M-tile m = ws4 ----
  const int nl     = l & 15;
  const int quad   = l >> 4;
  const int g_role = nl & 3;        // gate index (i,f,g,o)
  const int jh     = nl >> 2;       // hidden col within block
  const int col_h  = bk * 4 + jh;
  const float bias_reg = bias[g_role * 1024 + col_h];
  float c_reg[4], mask_reg[4];
  #pragma unroll
  for (int r = 0; r < 4; ++r) {
    const int b = ws4 * 16 + quad * 4 + r;
    c_reg[r]    = c0[b * 1024 + col_h];
    mask_reg[r] = mask_h[b * 1024 + col_h];
  }

  // ---- prologue: x-waves compute step-0 x-partials into ldsX[0] ----
  if (xw) {
    f32x4 acc[4] = { {0,0,0,0}, {0,0,0,0}, {0,0,0,0}, {0,0,0,0} };
    #pragma unroll
    for (int m = 0; m < 4; ++m)
      #pragma unroll
      for (int kw = 0; kw < 8; ++kw) {
        bf16x8 a = ApV[(m * 32 + ws4 * 8 + kw) * 64 + l];
        acc[m] = __builtin_amdgcn_mfma_f32_16x16x32_bf16(a, wf[kw], acc[m], 0, 0, 0);
      }
    #pragma unroll
    for (int m = 0; m < 4; ++m) ldsX[0][ws4][m][l] = acc[m];
  }

  #pragma unroll 1
  for (int s = 0; s < 256; ++s) {
    if (!xw) {
      // recurrent GEMM on mh[s&1], K-slice ws4*256 .. +256
      const bf16x8* mb = (s & 1) ? mhV1 : mhV0;
      f32x4 acc[4] = { {0,0,0,0}, {0,0,0,0}, {0,0,0,0}, {0,0,0,0} };
      #pragma unroll
      for (int m = 0; m < 4; ++m)
        #pragma unroll
        for (int kw = 0; kw < 8; ++kw) {
          bf16x8 a = mb[(m * 32 + ws4 * 8 + kw) * 64 + l];
          acc[m] = __builtin_amdgcn_mfma_f32_16x16x32_bf16(a, wf[kw], acc[m], 0, 0, 0);
        }
      #pragma unroll
      for (int m = 0; m < 4; ++m) ldsH[ws4][m][l] = acc[m];
    } else if (s + 1 < 256) {
      // x-projection GEMM for step s+1 (pipelined)
      f32x4 acc[4] = { {0,0,0,0}, {0,0,0,0}, {0,0,0,0}, {0,0,0,0} };
      #pragma unroll
      for (int m = 0; m < 4; ++m)
        #pragma unroll
        for (int kw = 0; kw < 8; ++kw) {
          bf16x8 a = ApV[(((s + 1) * 4 + m) * 32 + ws4 * 8 + kw) * 64 + l];
          acc[m] = __builtin_amdgcn_mfma_f32_16x16x32_bf16(a, wf[kw], acc[m], 0, 0, 0);
        }
      #pragma unroll
      for (int m = 0; m < 4; ++m) ldsX[(s + 1) & 1][ws4][m][l] = acc[m];
    }
    __syncthreads();

    if (!xw) {
      const int m = ws4;   // this wave's M-tile
      f32x4 t = ldsX[s & 1][0][m][l];
      #pragma unroll
      for (int ww = 1; ww < 4; ++ww) t += ldsX[s & 1][ww][m][l];
      #pragma unroll
      for (int ww = 0; ww < 4; ++ww) t += ldsH[ww][m][l];

      u16* mo = (s & 1) ? mh0 : mh1;   // write mh(s+1) into the other buffer
      #pragma unroll
      for (int r = 0; r < 4; ++r) {
        const float gp = t[r] + bias_reg;
        const float v1 = __shfl_xor(gp, 1, 64);
        const float v2 = __shfl_xor(gp, 2, 64);
        const float v3 = __shfl_xor(gp, 3, 64);
        // gate j's value sits in arr[g_role ^ j]
        const float ig = pick4(g_role,     gp, v1, v2, v3);
        const float fg = pick4(g_role ^ 1, gp, v1, v2, v3);
        const float gg = pick4(g_role ^ 2, gp, v1, v2, v3);
        const float og = pick4(g_role ^ 3, gp, v1, v2, v3);
        const float iv = sigm(ig);
        const float fv = sigm(fg);
        const float gv = tanh_fast(gg);
        const float ov = sigm(og);
        const float cn = fv * c_reg[r] + iv * gv;
        const float hn = ov * tanh_fast(cn);
        c_reg[r] = cn;
        if (g_role == 0) {
          const int b = m * 16 + quad * 4 + r;
          out[((size_t)s * 64 + b) * 1024 + col_h] = hn;
          const int kwg = col_h >> 5;
          const int lp  = ((col_h >> 3) & 3) * 16 + (b & 15);
          mo[((m * 32 + kwg) * 64 + lp) * 8 + (col_h & 7)] = f2bf(hn * mask_reg[r]);
          if (s == 255) {
            out[16777216 + b * 1024 + col_h] = hn;           // h_n
            out[16777216 + 65536 + b * 1024 + col_h] = cn;   // c_n
          }
        }
      }
    }
    __threadfence();
    grid.sync();
  }
}

extern "C" void kernel_launch(void* const* d_in, const int* in_sizes, int n_in,
                              void* d_out, int out_size, void* d_ws, size_t ws_size,
                              hipStream_t stream)
{
  const float* x      = (const float*)d_in[0];
  const float* h0     = (const float*)d_in[1];
  const float* c0     = (const float*)d_in[2];
  const float* mask_x = (const float*)d_in[3];
  const float* mask_h = (const float*)d_in[4];
  const float* Wih    = (const float*)d_in[5];
  const float* Whh    = (const float*)d_in[6];
  const float* bih    = (const float*)d_in[7];
  const float* bhh    = (const float*)d_in[8];
  float* out = (float*)d_out;

  char* ws = (char*)d_ws;
  u16*   Wp   = (u16*)(ws + 0);
  u16*   Ap   = (u16*)(ws + 16777216);
  u16*   mh0  = (u16*)(ws + 50331648);
  u16*   mh1  = (u16*)(ws + 50462720);
  float* bias = (float*)(ws + 50593792);

  hipLaunchKernelGGL(prep_kernel, dim3(65536), dim3(256), 0, stream,
                     x, h0, mask_x, mask_h, Wih, Whh, bih, bhh,
                     Wp, Ap, mh0, bias);

  const u16* Ap_c = Ap; const u16* Wp_c = Wp; const float* bias_c = bias;
  const float* c0_c = c0; const float* mask_h_c = mask_h;
  void* args[] = { (void*)&Ap_c, (void*)&Wp_c, (void*)&bias_c,
                   (void*)&mh0, (void*)&mh1,
                   (void*)&c0_c, (void*)&mask_h_c, (void*)&out };
  hipLaunchCooperativeKernel((const void*)lstm_persist,
                             dim3(256), dim3(512), args, 0, stream);
}

// Round 3
// 4163.470 us; speedup vs baseline: 5.0643x; 5.0643x over previous
//
#include <hip/hip_runtime.h>
#include <stdint.h>
#include <stddef.h>

// Variational-dropout LSTM, SEQ=256, B=64, IN=H=1024, fp32 I/O.
//
// R3: back to per-step graph launches (R2 showed grid.sync ~80us/step —
// unusable). Three kernels:
//  - prep: bf16-swizzle Ap (masked x), Wihp/Whhp (gate-interleaved N, MFMA
//    fragment order), mh0, bias, c.
//  - xg_kernel: precompute x-projection gates as fp16 in per-lane C-fragment
//    layout (one-shot GEMM, removes half the K from every step).
//  - lstm_step x256: 256 blocks (all CUs), block owns 4 h-cols x 4 gates
//    (gate-interleaved: nl = jh*4+g). K=1024 split across 4 waves (no weight
//    duplication), LDS f32x4 reduce, shfl_xor gate gather, block-local cell.
// If ws_size < 185 MB, falls back to folding the x-GEMM into each step
// (needs only the R1-proven 50.87 MB).

#define SEQ 256

typedef __attribute__((ext_vector_type(8))) __bf16 bf16x8;
typedef __attribute__((ext_vector_type(4))) float  f32x4;
typedef __attribute__((ext_vector_type(4))) _Float16 f16x4;
typedef unsigned short u16;

__device__ __forceinline__ u16 f2bf(float f) {
  union { float f; unsigned u; } v; v.f = f;
  unsigned r = v.u + 0x7FFFu + ((v.u >> 16) & 1u);   // RNE
  return (u16)(r >> 16);
}
__device__ __forceinline__ float sigm(float x) {
  return __builtin_amdgcn_rcpf(1.f + __expf(-x));
}
__device__ __forceinline__ float tanh_fast(float x) {
  float xc = fminf(15.f, fmaxf(-15.f, x));
  float t = __expf(-2.f * xc);
  return (1.f - t) * __builtin_amdgcn_rcpf(1.f + t);
}
__device__ __forceinline__ float pick4(int idx, float v0, float v1, float v2, float v3) {
  float lo = (idx & 1) ? v1 : v0;
  float hi = (idx & 1) ? v3 : v2;
  return (idx & 2) ? hi : lo;
}

// ws layout (bytes):
//  Wihp @ 0         : [bk 256][kcw 32][l 64][e 8] bf16 = 8388608
//  Whhp @ 8388608   : same = 8388608
//  Ap   @ 16777216  : [s 256][m 4][kwg 32][l 64][e 8] bf16 = 33554432
//  mh0  @ 50331648  : [m 4][kwg 32][l 64][e 8] bf16 = 131072
//  mh1  @ 50462720  : 131072
//  bias @ 50593792  : 4096 f32 = 16384
//  c    @ 50610176  : [b 64][col 1024] f32 = 262144        (base end: 50872320)
//  xg   @ 50872320  : [s 256][bk 256][m 4][l 64][r 4] fp16 = 134217728
//  full end: 185090048

__global__ __launch_bounds__(256) void prep_kernel(
    const float* __restrict__ x, const float* __restrict__ h0,
    const float* __restrict__ c0, const float* __restrict__ mask_x,
    const float* __restrict__ mask_h, const float* __restrict__ Wih,
    const float* __restrict__ Whh, const float* __restrict__ bih,
    const float* __restrict__ bhh,
    u16* __restrict__ Wihp, u16* __restrict__ Whhp, u16* __restrict__ Ap,
    u16* __restrict__ mhp0, float* __restrict__ bias, float* __restrict__ c)
{
  const unsigned idx = blockIdx.x * 256u + threadIdx.x;  // 0 .. 16777215

  // Ap[s][m][kwg][l][e] = bf16( x[s][b][k] * mask_x[b][k] )
  {
    const unsigned e   = idx & 7u;
    const unsigned l   = (idx >> 3) & 63u;
    const unsigned kwg = (idx >> 9) & 31u;
    const unsigned m   = (idx >> 14) & 3u;
    const unsigned s   = idx >> 16;
    const unsigned b   = m * 16u + (l & 15u);
    const unsigned k   = kwg * 32u + (l >> 4) * 8u + e;
    Ap[idx] = f2bf(x[((size_t)s * 64u + b) * 1024u + k] * mask_x[b * 1024u + k]);
  }
  // W swizzles: [bk][kcw][l][e], n = (nl&3)*1024 + bk*4 + (nl>>2)
  if (idx < 4194304u) {
    const unsigned e   = idx & 7u;
    const unsigned l   = (idx >> 3) & 63u;
    const unsigned kcw = (idx >> 9) & 31u;
    const unsigned bk  = idx >> 14;
    const unsigned nl  = l & 15u;
    const unsigned n   = (nl & 3u) * 1024u + bk * 4u + (nl >> 2);
    const unsigned k   = kcw * 32u + (l >> 4) * 8u + e;
    Wihp[idx] = f2bf(Wih[n * 1024u + k]);
    Whhp[idx] = f2bf(Whh[n * 1024u + k]);
  }
  // mh0[m][kwg][l][e] = bf16(h0 * mask_h), plus c init
  if (idx < 65536u) {
    const unsigned e   = idx & 7u;
    const unsigned l   = (idx >> 3) & 63u;
    const unsigned kwg = (idx >> 9) & 31u;
    const unsigned m   = idx >> 14;
    const unsigned b   = m * 16u + (l & 15u);
    const unsigned k   = kwg * 32u + (l >> 4) * 8u + e;
    mhp0[idx] = f2bf(h0[b * 1024u + k] * mask_h[b * 1024u + k]);
    c[idx] = c0[idx];
  }
  if (idx < 4096u) bias[idx] = bih[idx] + bhh[idx];
}

// x-projection GEMM: xg[s][bk][m][l][r] (fp16, C-fragment layout).
// grid (nq=64, s=256), block 256 (4 waves, K-split 256 each).
__global__ __launch_bounds__(256) void xg_kernel(
    const u16* __restrict__ Ap, const u16* __restrict__ Wihp,
    _Float16* __restrict__ xg)
{
  __shared__ f32x4 lds[4][4][4][64];   // [w][n][m][l] 64 KB

  const int tid = threadIdx.x;
  const int w   = tid >> 6;
  const int l   = tid & 63;
  const int nq  = blockIdx.x;   // 4 bk-units
  const int s   = blockIdx.y;

  const bf16x8* ApV = (const bf16x8*)Ap;
  const bf16x8* WV  = (const bf16x8*)Wihp;

  f32x4 acc[4][4];   // [n][m]
  #pragma unroll
  for (int n = 0; n < 4; ++n)
    #pragma unroll
    for (int m = 0; m < 4; ++m) acc[n][m] = (f32x4){0.f, 0.f, 0.f, 0.f};

  #pragma unroll 2
  for (int kw = 0; kw < 8; ++kw) {
    bf16x8 a[4];
    #pragma unroll
    for (int m = 0; m < 4; ++m)
      a[m] = ApV[((s * 4 + m) * 32 + w * 8 + kw) * 64 + l];
    #pragma unroll
    for (int n = 0; n < 4; ++n) {
      bf16x8 b = WV[((nq * 4 + n) * 32 + w * 8 + kw) * 64 + l];
      #pragma unroll
      for (int m = 0; m < 4; ++m)
        acc[n][m] = __builtin_amdgcn_mfma_f32_16x16x32_bf16(a[m], b, acc[n][m], 0, 0, 0);
    }
  }
  #pragma unroll
  for (int n = 0; n < 4; ++n)
    #pragma unroll
    for (int m = 0; m < 4; ++m) lds[w][n][m][l] = acc[n][m];
  __syncthreads();

  // wave w reduces m-tile w for all n, writes fp16
  #pragma unroll
  for (int n = 0; n < 4; ++n) {
    f32x4 t = lds[0][n][w][l];
    #pragma unroll
    for (int ww = 1; ww < 4; ++ww) t += lds[ww][n][w][l];
    f16x4 o;
    #pragma unroll
    for (int r = 0; r < 4; ++r) o[r] = (_Float16)t[r];
    *(f16x4*)&xg[((((size_t)s * 256 + nq * 4 + n) * 4 + w) * 64 + l) * 4] = o;
  }
}

__global__ __launch_bounds__(256) void lstm_step(
    const u16* __restrict__ Ap,     // fallback only
    const u16* __restrict__ Wihp,   // fallback only
    const u16* __restrict__ Whhp,
    const _Float16* __restrict__ xg,  // null => fallback (fold x-GEMM)
    const float* __restrict__ bias,
    const u16* __restrict__ mh_in, u16* __restrict__ mh_out,
    float* __restrict__ c, const float* __restrict__ mask_h,
    float* __restrict__ out, int s)
{
  __shared__ f32x4 lds[4][4][64];   // [w][m][l] 16 KB

  const int tid = threadIdx.x;
  const int w   = tid >> 6;      // K-slice
  const int l   = tid & 63;
  const int bk  = blockIdx.x;    // 4 h-cols

  const bf16x8* mb = (const bf16x8*)mh_in;
  const bf16x8* WH = (const bf16x8*)Whhp;

  f32x4 acc[4] = { {0,0,0,0}, {0,0,0,0}, {0,0,0,0}, {0,0,0,0} };

  #pragma unroll 2
  for (int kw = 0; kw < 8; ++kw) {
    bf16x8 b = WH[(bk * 32 + w * 8 + kw) * 64 + l];
    #pragma unroll
    for (int m = 0; m < 4; ++m) {
      bf16x8 a = mb[(m * 32 + w * 8 + kw) * 64 + l];
      acc[m] = __builtin_amdgcn_mfma_f32_16x16x32_bf16(a, b, acc[m], 0, 0, 0);
    }
  }
  if (xg == nullptr) {   // fold x-projection (fallback when ws is small)
    const bf16x8* ApV = (const bf16x8*)Ap;
    const bf16x8* WI  = (const bf16x8*)Wihp;
    #pragma unroll 2
    for (int kw = 0; kw < 8; ++kw) {
      bf16x8 b = WI[(bk * 32 + w * 8 + kw) * 64 + l];
      #pragma unroll
      for (int m = 0; m < 4; ++m) {
        bf16x8 a = ApV[((s * 4 + m) * 32 + w * 8 + kw) * 64 + l];
        acc[m] = __builtin_amdgcn_mfma_f32_16x16x32_bf16(a, b, acc[m], 0, 0, 0);
      }
    }
  }
  #pragma unroll
  for (int m = 0; m < 4; ++m) lds[w][m][l] = acc[m];
  __syncthreads();

  // wave w owns m-tile w
  f32x4 t = lds[0][w][l];
  #pragma unroll
  for (int ww = 1; ww < 4; ++ww) t += lds[ww][w][l];

  const int nl     = l & 15;
  const int quad   = l >> 4;
  const int g_role = nl & 3;
  const int jh     = nl >> 2;
  const int col_h  = bk * 4 + jh;

  if (xg != nullptr) {
    f16x4 xv = *(const f16x4*)&xg[((((size_t)s * 256 + bk) * 4 + w) * 64 + l) * 4];
    #pragma unroll
    for (int r = 0; r < 4; ++r) t[r] += (float)xv[r];
  }
  const float bias_reg = bias[g_role * 1024 + col_h];
  const int kwg = col_h >> 5;
  const int lp  = ((col_h >> 3) & 3) * 16;

  #pragma unroll
  for (int r = 0; r < 4; ++r) {
    const int b_row = w * 16 + quad * 4 + r;
    const float gp = t[r] + bias_reg;
    const float v1 = __shfl_xor(gp, 1, 64);
    const float v2 = __shfl_xor(gp, 2, 64);
    const float v3 = __shfl_xor(gp, 3, 64);
    const float ig = pick4(g_role,     gp, v1, v2, v3);
    const float fg = pick4(g_role ^ 1, gp, v1, v2, v3);
    const float gg = pick4(g_role ^ 2, gp, v1, v2, v3);
    const float og = pick4(g_role ^ 3, gp, v1, v2, v3);
    const float iv = sigm(ig);
    const float fv = sigm(fg);
    const float gv = tanh_fast(gg);
    const float ov = sigm(og);
    const float cold = c[b_row * 1024 + col_h];
    const float cn = fv * cold + iv * gv;
    const float hn = ov * tanh_fast(cn);
    if (g_role == 0) {
      c[b_row * 1024 + col_h] = cn;
      out[((size_t)s * 64 + b_row) * 1024 + col_h] = hn;
      mh_out[((w * 32 + kwg) * 64 + (lp + (b_row & 15))) * 8 + (col_h & 7)] =
          f2bf(hn * mask_h[b_row * 1024 + col_h]);
      if (s == SEQ - 1) {
        out[16777216 + b_row * 1024 + col_h] = hn;           // h_n
        out[16777216 + 65536 + b_row * 1024 + col_h] = cn;   // c_n
      }
    }
  }
}

extern "C" void kernel_launch(void* const* d_in, const int* in_sizes, int n_in,
                              void* d_out, int out_size, void* d_ws, size_t ws_size,
                              hipStream_t stream)
{
  const float* x      = (const float*)d_in[0];
  const float* h0     = (const float*)d_in[1];
  const float* c0     = (const float*)d_in[2];
  const float* mask_x = (const float*)d_in[3];
  const float* mask_h = (const float*)d_in[4];
  const float* Wih    = (const float*)d_in[5];
  const float* Whh    = (const float*)d_in[6];
  const float* bih    = (const float*)d_in[7];
  const float* bhh    = (const float*)d_in[8];
  float* out = (float*)d_out;

  char* ws = (char*)d_ws;
  u16*      Wihp = (u16*)(ws + 0);
  u16*      Whhp = (u16*)(ws + 8388608);
  u16*      Ap   = (u16*)(ws + 16777216);
  u16*      mh0  = (u16*)(ws + 50331648);
  u16*      mh1  = (u16*)(ws + 50462720);
  float*    bias = (float*)(ws + 50593792);
  float*    c    = (float*)(ws + 50610176);
  _Float16* xg   = (_Float16*)(ws + 50872320);
  const bool use_xg = (ws_size >= (size_t)185090048);

  hipLaunchKernelGGL(prep_kernel, dim3(65536), dim3(256), 0, stream,
                     x, h0, c0, mask_x, mask_h, Wih, Whh, bih, bhh,
                     Wihp, Whhp, Ap, mh0, bias, c);

  if (use_xg)
    hipLaunchKernelGGL(xg_kernel, dim3(64, 256), dim3(256), 0, stream,
                       Ap, Wihp, xg);

  const _Float16* xg_arg = use_xg ? xg : (const _Float16*)nullptr;
  for (int s = 0; s < SEQ; ++s) {
    const u16* mi = (s & 1) ? mh1 : mh0;
    u16*       mo = (s & 1) ? mh0 : mh1;
    hipLaunchKernelGGL(lstm_step, dim3(256), dim3(256), 0, stream,
                       Ap, Wihp, Whhp, xg_arg, bias, mi, mo, c, mask_h, out, s);
  }
}